// Round 5
// baseline (392.754 us; speedup 1.0000x reference)
//
#include <hip/hip_runtime.h>

#define NN 200000
#define NE 1000000
#define DD 64
#define NCHUNK 196   // ceil(NN / 1024)

typedef __bf16 bf16x4 __attribute__((ext_vector_type(4)));
typedef __bf16 bf16x8 __attribute__((ext_vector_type(8)));
typedef float  f32x4  __attribute__((ext_vector_type(4)));

// Load 8 consecutive f32 and convert to bf16x8 (RNE).
static __device__ __forceinline__ bf16x8 pack8(const float* __restrict__ p) {
    float4 a = *reinterpret_cast<const float4*>(p);
    float4 b = *reinterpret_cast<const float4*>(p + 4);
    bf16x8 r;
    r[0] = (__bf16)a.x; r[1] = (__bf16)a.y; r[2] = (__bf16)a.z; r[3] = (__bf16)a.w;
    r[4] = (__bf16)b.x; r[5] = (__bf16)b.y; r[6] = (__bf16)b.z; r[7] = (__bf16)b.w;
    return r;
}

// ---------- Streaming bf16 conversions ----------

__global__ __launch_bounds__(256) void k_conv_rev(const float* __restrict__ review,
                                                  __bf16* __restrict__ reviewb) {
    const size_t nchunks = (size_t)NE * DD / 8;
    for (size_t i = blockIdx.x * blockDim.x + threadIdx.x; i < nchunks;
         i += (size_t)gridDim.x * blockDim.x)
        *reinterpret_cast<bf16x8*>(reviewb + i * 8) = pack8(review + i * 8);
}

__global__ __launch_bounds__(256) void k_conv_pair(const float* __restrict__ f2,
                                                   const float* __restrict__ f3,
                                                   __bf16* __restrict__ f2b,
                                                   __bf16* __restrict__ f3b) {
    const size_t per = (size_t)NN * DD / 8;
    for (size_t i = blockIdx.x * blockDim.x + threadIdx.x; i < 2 * per;
         i += (size_t)gridDim.x * blockDim.x) {
        if (i < per) *reinterpret_cast<bf16x8*>(f2b + i * 8) = pack8(f2 + i * 8);
        else {
            const size_t j = i - per;
            *reinterpret_cast<bf16x8*>(f3b + j * 8) = pack8(f3 + j * 8);
        }
    }
}

// ---------- CSR construction ----------

__global__ __launch_bounds__(256) void k_hist(const int* __restrict__ dst,
                                              int* __restrict__ counts) {
    for (int e = blockIdx.x * blockDim.x + threadIdx.x; e < NE;
         e += gridDim.x * blockDim.x)
        atomicAdd(&counts[dst[e]], 1);
}

__global__ __launch_bounds__(256) void k_chunk_sums(const int* __restrict__ counts,
                                                    int* __restrict__ csum) {
    const int b = blockIdx.x, tid = threadIdx.x;
    const int base = b * 1024 + tid * 4;
    int s = 0;
#pragma unroll
    for (int j = 0; j < 4; ++j) {
        const int i = base + j;
        if (i < NN) s += counts[i];
    }
#pragma unroll
    for (int d = 32; d > 0; d >>= 1) s += __shfl_down(s, d);
    __shared__ int wsum[4];
    if ((tid & 63) == 0) wsum[tid >> 6] = s;
    __syncthreads();
    if (tid == 0) csum[b] = wsum[0] + wsum[1] + wsum[2] + wsum[3];
}

__global__ void k_scan_chunks(const int* __restrict__ csum, int* __restrict__ cofs) {
    if (threadIdx.x == 0 && blockIdx.x == 0) {
        int acc = 0;
        for (int i = 0; i < NCHUNK; ++i) { cofs[i] = acc; acc += csum[i]; }
    }
}

__global__ __launch_bounds__(256) void k_chunk_scan(const int* __restrict__ counts,
                                                    const int* __restrict__ cofs,
                                                    int* __restrict__ offs,
                                                    int* __restrict__ cursor) {
    const int b = blockIdx.x, tid = threadIdx.x;
    const int lane = tid & 63, wv = tid >> 6;
    const int base = b * 1024 + tid * 4;
    int c[4];
#pragma unroll
    for (int j = 0; j < 4; ++j) {
        const int i = base + j;
        c[j] = (i < NN) ? counts[i] : 0;
    }
    const int ls = c[0] + c[1] + c[2] + c[3];
    int v = ls;
#pragma unroll
    for (int d = 1; d < 64; d <<= 1) {
        const int u = __shfl_up(v, d);
        if (lane >= d) v += u;
    }
    __shared__ int wsum[4];
    if (lane == 63) wsum[wv] = v;
    __syncthreads();
    int wbase = 0;
    for (int w = 0; w < wv; ++w) wbase += wsum[w];
    int excl = cofs[b] + wbase + (v - ls);
#pragma unroll
    for (int j = 0; j < 4; ++j) {
        const int i = base + j;
        if (i < NN) { offs[i] = excl; cursor[i] = excl; }
        excl += c[j];
    }
}

__global__ __launch_bounds__(256) void k_permfill(const int* __restrict__ dst,
                                                  const int* __restrict__ src,
                                                  const float* __restrict__ ci,
                                                  int* __restrict__ cursor,
                                                  int2* __restrict__ epack,
                                                  float* __restrict__ ecis) {
    for (int e = blockIdx.x * blockDim.x + threadIdx.x; e < NE;
         e += gridDim.x * blockDim.x) {
        const int s = src[e];
        const int pos = atomicAdd(&cursor[dst[e]], 1);
        epack[pos] = make_int2(e, s);
        ecis[pos] = ci[s];
    }
}

// ---------- Fused pull + node-GEMM ----------
// Block = 256 threads = 16 quarters = 16 nodes = one MFMA A-tile.
// Quarter q accumulates node n's sums (lane l16 owns cols l16*4..+3), then
// the block does out_re = hx@W1^T, out_rst = s2 + hx@W2^T via 16x16x32 MFMA.
template<int REVB>
__global__ __launch_bounds__(256) void k_pull_fused(
    const int2* __restrict__ epack, const float* __restrict__ ecis,
    const int* __restrict__ offs, const int* __restrict__ counts,
    const float* __restrict__ review, const __bf16* __restrict__ reviewb,
    const float* __restrict__ ci,
    const __bf16* __restrict__ f2b, const __bf16* __restrict__ f3b,
    const float* __restrict__ W1, const float* __restrict__ W2,
    float* __restrict__ out_rst, float* __restrict__ out_re,
    float* __restrict__ out_id)
{
    __shared__ __bf16 At[16][64];   // bf16(cid * hx) tile
    __shared__ float  S2[16][64];   // cid * sum(f2[s]*cis) tile

    const int tid = threadIdx.x;
    const int l16 = tid & 15;
    const int q   = tid >> 4;               // 0..15: tile row / node-in-block
    const int n   = blockIdx.x * 16 + q;

    const int beg = offs[n];
    const int cnt = counts[n];

    float4 ax = {0.f,0.f,0.f,0.f}, a2 = {0.f,0.f,0.f,0.f}, a3 = {0.f,0.f,0.f,0.f};

    for (int k = 0; k < cnt; ++k) {
        const int2 es = epack[beg + k];     // {edge, src} (broadcast within quarter)
        const float cis = ecis[beg + k];
        float4 r;
        if (REVB) {
            bf16x4 rb = *reinterpret_cast<const bf16x4*>(
                reviewb + (size_t)es.x * DD + l16 * 4);
            r.x = (float)rb[0]; r.y = (float)rb[1]; r.z = (float)rb[2]; r.w = (float)rb[3];
        } else {
            r = *reinterpret_cast<const float4*>(review + (size_t)es.x * DD + l16 * 4);
        }
        const bf16x4 p2 = *reinterpret_cast<const bf16x4*>(f2b + (size_t)es.y * DD + l16 * 4);
        const bf16x4 p3 = *reinterpret_cast<const bf16x4*>(f3b + (size_t)es.y * DD + l16 * 4);
        ax.x = fmaf(r.x, cis, ax.x); ax.y = fmaf(r.y, cis, ax.y);
        ax.z = fmaf(r.z, cis, ax.z); ax.w = fmaf(r.w, cis, ax.w);
        a2.x = fmaf((float)p2[0], cis, a2.x); a2.y = fmaf((float)p2[1], cis, a2.y);
        a2.z = fmaf((float)p2[2], cis, a2.z); a2.w = fmaf((float)p2[3], cis, a2.w);
        a3.x = fmaf((float)p3[0], cis, a3.x); a3.y = fmaf((float)p3[1], cis, a3.y);
        a3.z = fmaf((float)p3[2], cis, a3.z); a3.w = fmaf((float)p3[3], cis, a3.w);
    }

    const float cid = ci[n];

    // out_id is final here.
    float4 v3 = {a3.x * cid, a3.y * cid, a3.z * cid, a3.w * cid};
    *reinterpret_cast<float4*>(out_id + (size_t)n * DD + l16 * 4) = v3;

    // Stage GEMM input tiles.
    bf16x4 hb;
    hb[0] = (__bf16)(ax.x * cid); hb[1] = (__bf16)(ax.y * cid);
    hb[2] = (__bf16)(ax.z * cid); hb[3] = (__bf16)(ax.w * cid);
    *reinterpret_cast<bf16x4*>(&At[q][l16 * 4]) = hb;
    float4 s2v = {a2.x * cid, a2.y * cid, a2.z * cid, a2.w * cid};
    *reinterpret_cast<float4*>(&S2[q][l16 * 4]) = s2v;
    __syncthreads();

    // GEMM: wave w computes col-block w for both W1 (out_re) and W2 (out_rst).
    const int w  = tid >> 6;          // 0..3
    const int lq = (tid & 63) >> 4;   // 0..3
    bf16x8 w1f[2], w2f[2];
#pragma unroll
    for (int kk = 0; kk < 2; ++kk) {
        const int off = (w * 16 + l16) * DD + kk * 32 + lq * 8;
        w1f[kk] = pack8(W1 + off);
        w2f[kk] = pack8(W2 + off);
    }
    const bf16x8 a0 = *reinterpret_cast<const bf16x8*>(&At[l16][lq * 8]);
    const bf16x8 a1 = *reinterpret_cast<const bf16x8*>(&At[l16][lq * 8 + 32]);

    const f32x4 zero = {0.f, 0.f, 0.f, 0.f};
    f32x4 acc1 = zero, acc2 = zero;
    acc1 = __builtin_amdgcn_mfma_f32_16x16x32_bf16(a0, w1f[0], acc1, 0, 0, 0);
    acc1 = __builtin_amdgcn_mfma_f32_16x16x32_bf16(a1, w1f[1], acc1, 0, 0, 0);
    acc2 = __builtin_amdgcn_mfma_f32_16x16x32_bf16(a0, w2f[0], acc2, 0, 0, 0);
    acc2 = __builtin_amdgcn_mfma_f32_16x16x32_bf16(a1, w2f[1], acc2, 0, 0, 0);

    const int base = blockIdx.x * 16;
#pragma unroll
    for (int i = 0; i < 4; ++i) {
        const int row = lq * 4 + i;
        const size_t o = (size_t)(base + row) * DD + w * 16 + l16;
        out_re[o]  = acc1[i];
        out_rst[o] = acc2[i] + S2[row][w * 16 + l16];
    }
}

// ---------- Fallback (round-2 proven kernel) if ws too small ----------
__global__ __launch_bounds__(256) void gcn_mfma_kernel(
    const int* __restrict__ src, const int* __restrict__ dst,
    const float* __restrict__ review, const float* __restrict__ ci,
    const float* __restrict__ W1, const float* __restrict__ W2,
    const float* __restrict__ f2, const float* __restrict__ f3,
    float* __restrict__ out)
{
    float* out_rst = out;
    float* out_re  = out + (size_t)NN * DD;
    float* out_id  = out + 2 * (size_t)NN * DD;
    const int lane = threadIdx.x & 63;
    const int l16  = lane & 15;
    const int lq   = lane >> 4;
    const int wid  = blockIdx.x * (blockDim.x >> 6) + (threadIdx.x >> 6);
    const int nw   = gridDim.x * (blockDim.x >> 6);

    bf16x8 w1f[4][2], w2f[4][2];
#pragma unroll
    for (int c = 0; c < 4; ++c)
#pragma unroll
        for (int kk = 0; kk < 2; ++kk) {
            const int off = (c * 16 + l16) * DD + kk * 32 + lq * 8;
            w1f[c][kk] = pack8(W1 + off);
            w2f[c][kk] = pack8(W2 + off);
        }
    const f32x4 zero = {0.f, 0.f, 0.f, 0.f};
    for (int t = wid; t < NE / 16; t += nw) {
        const int e0 = t * 16;
        const float* xr = review + (size_t)(e0 + l16) * DD + lq * 8;
        const bf16x8 a0 = pack8(xr);
        const bf16x8 a1 = pack8(xr + 32);
        f32x4 acc1[4], acc2[4];
#pragma unroll
        for (int c = 0; c < 4; ++c) { acc1[c] = zero; acc2[c] = zero; }
#pragma unroll
        for (int c = 0; c < 4; ++c) {
            acc1[c] = __builtin_amdgcn_mfma_f32_16x16x32_bf16(a0, w1f[c][0], acc1[c], 0, 0, 0);
            acc1[c] = __builtin_amdgcn_mfma_f32_16x16x32_bf16(a1, w1f[c][1], acc1[c], 0, 0, 0);
            acc2[c] = __builtin_amdgcn_mfma_f32_16x16x32_bf16(a0, w2f[c][0], acc2[c], 0, 0, 0);
            acc2[c] = __builtin_amdgcn_mfma_f32_16x16x32_bf16(a1, w2f[c][1], acc2[c], 0, 0, 0);
        }
        int sA[4], dA[4]; float cf[4];
#pragma unroll
        for (int i = 0; i < 4; ++i) {
            const int e = e0 + lq * 4 + i;
            sA[i] = src[e]; dA[i] = dst[e];
            cf[i] = ci[sA[i]] * ci[dA[i]];
        }
#pragma unroll
        for (int i = 0; i < 4; ++i) {
            const size_t so = (size_t)sA[i] * DD;
            const size_t dofs = (size_t)dA[i] * DD;
            const float c_ = cf[i];
#pragma unroll
            for (int c = 0; c < 4; ++c) {
                const int col = c * 16 + l16;
                atomicAdd(out_re  + dofs + col, acc1[c][i] * c_);
                atomicAdd(out_rst + dofs + col, (f2[so + col] + acc2[c][i]) * c_);
                atomicAdd(out_id  + dofs + col, f3[so + col] * c_);
            }
        }
    }
}

extern "C" void kernel_launch(void* const* d_in, const int* in_sizes, int n_in,
                              void* d_out, int out_size, void* d_ws, size_t ws_size,
                              hipStream_t stream) {
    const int*   src    = (const int*)d_in[0];
    const int*   dst    = (const int*)d_in[1];
    const float* review = (const float*)d_in[2];
    const float* ci     = (const float*)d_in[3];
    // d_in[4] = feature (unused by the reference computation)
    const float* W1     = (const float*)d_in[5];
    const float* W2     = (const float*)d_in[6];
    const float* f2     = (const float*)d_in[7];
    const float* f3     = (const float*)d_in[8];
    float* out = (float*)d_out;
    float* out_rst = out;
    float* out_re  = out + (size_t)NN * DD;
    float* out_id  = out + 2 * (size_t)NN * DD;

    // counts | offs | cursor | csum | cofs | epack | ecis | f2b | f3b [| reviewb]
    const size_t NEED2 = sizeof(int) * ((size_t)3 * NN + 512) +
                         sizeof(int2) * (size_t)NE + sizeof(float) * (size_t)NE +
                         2 * sizeof(__bf16) * (size_t)NN * DD;
    const size_t NEED1 = NEED2 + sizeof(__bf16) * (size_t)NE * DD;

    if (ws_size < NEED2) {
        hipMemsetAsync(out, 0, (size_t)out_size * sizeof(float), stream);
        gcn_mfma_kernel<<<2048, 256, 0, stream>>>(src, dst, review, ci, W1, W2, f2, f3, out);
        return;
    }

    char* w = (char*)d_ws;
    int* counts   = (int*)w;     w += (size_t)NN * 4;
    int* offs     = (int*)w;     w += (size_t)NN * 4;
    int* cursor   = (int*)w;     w += (size_t)NN * 4;
    int* csum     = (int*)w;     w += 256 * 4;
    int* cofs     = (int*)w;     w += 256 * 4;
    int2* epack   = (int2*)w;    w += (size_t)NE * 8;
    float* ecis   = (float*)w;   w += (size_t)NE * 4;
    __bf16* f2b   = (__bf16*)w;  w += (size_t)NN * DD * 2;
    __bf16* f3b   = (__bf16*)w;  w += (size_t)NN * DD * 2;
    __bf16* reviewb = (__bf16*)w;
    const bool tier1 = (ws_size >= NEED1);

    hipMemsetAsync(counts, 0, (size_t)NN * 4, stream);
    k_hist      <<<1024, 256, 0, stream>>>(dst, counts);
    if (tier1) k_conv_rev<<<2048, 256, 0, stream>>>(review, reviewb);
    k_conv_pair <<<2048, 256, 0, stream>>>(f2, f3, f2b, f3b);
    k_chunk_sums<<<NCHUNK, 256, 0, stream>>>(counts, csum);
    k_scan_chunks<<<1, 64, 0, stream>>>(csum, cofs);
    k_chunk_scan<<<NCHUNK, 256, 0, stream>>>(counts, cofs, offs, cursor);
    k_permfill  <<<1024, 256, 0, stream>>>(dst, src, ci, cursor, epack, ecis);
    if (tier1)
        k_pull_fused<1><<<NN / 16, 256, 0, stream>>>(epack, ecis, offs, counts,
            review, reviewb, ci, f2b, f3b, W1, W2, out_rst, out_re, out_id);
    else
        k_pull_fused<0><<<NN / 16, 256, 0, stream>>>(epack, ecis, offs, counts,
            review, reviewb, ci, f2b, f3b, W1, W2, out_rst, out_re, out_id);
}

// Round 6
// 294.748 us; speedup vs baseline: 1.3325x; 1.3325x over previous
//
#include <hip/hip_runtime.h>

#define NN 200000
#define NE 1000000
#define DD 64
#define NCHUNK 196   // ceil(NN / 1024)

typedef __bf16 bf16x4 __attribute__((ext_vector_type(4)));
typedef __bf16 bf16x8 __attribute__((ext_vector_type(8)));
typedef float  f32x4  __attribute__((ext_vector_type(4)));

static __device__ __forceinline__ bf16x8 pack8(const float* __restrict__ p) {
    float4 a = *reinterpret_cast<const float4*>(p);
    float4 b = *reinterpret_cast<const float4*>(p + 4);
    bf16x8 r;
    r[0] = (__bf16)a.x; r[1] = (__bf16)a.y; r[2] = (__bf16)a.z; r[3] = (__bf16)a.w;
    r[4] = (__bf16)b.x; r[5] = (__bf16)b.y; r[6] = (__bf16)b.z; r[7] = (__bf16)b.w;
    return r;
}

static __device__ __forceinline__ bf16x8 pack8s(const float* __restrict__ p, float c) {
    float4 a = *reinterpret_cast<const float4*>(p);
    float4 b = *reinterpret_cast<const float4*>(p + 4);
    bf16x8 r;
    r[0] = (__bf16)(a.x * c); r[1] = (__bf16)(a.y * c);
    r[2] = (__bf16)(a.z * c); r[3] = (__bf16)(a.w * c);
    r[4] = (__bf16)(b.x * c); r[5] = (__bf16)(b.y * c);
    r[6] = (__bf16)(b.z * c); r[7] = (__bf16)(b.w * c);
    return r;
}

// ---------- Prep: histogram (blocks 0..1023) + ci-folded bf16 conv ----------
__global__ __launch_bounds__(256) void k_prep(
    const int* __restrict__ dst, const float* __restrict__ f2,
    const float* __restrict__ f3, const float* __restrict__ ci,
    int* __restrict__ counts, __bf16* __restrict__ f2c, __bf16* __restrict__ f3c)
{
    const int b = blockIdx.x;
    if (b < 1024) {
        for (int e = b * 256 + threadIdx.x; e < NE; e += 1024 * 256)
            atomicAdd(&counts[dst[e]], 1);
    } else {
        const size_t per = (size_t)NN * DD / 8;     // 8-elem chunks per array
        const size_t stride = (size_t)(gridDim.x - 1024) * 256;
        for (size_t i = (size_t)(b - 1024) * 256 + threadIdx.x; i < per; i += stride) {
            const int row = (int)(i >> 3);
            const float c = ci[row];
            *reinterpret_cast<bf16x8*>(f2c + i * 8) = pack8s(f2 + i * 8, c);
            *reinterpret_cast<bf16x8*>(f3c + i * 8) = pack8s(f3 + i * 8, c);
        }
    }
}

// ---------- CSR scan ----------
__global__ __launch_bounds__(256) void k_chunk_sums(const int* __restrict__ counts,
                                                    int* __restrict__ csum) {
    const int b = blockIdx.x, tid = threadIdx.x;
    const int base = b * 1024 + tid * 4;
    int s = 0;
#pragma unroll
    for (int j = 0; j < 4; ++j) {
        const int i = base + j;
        if (i < NN) s += counts[i];
    }
#pragma unroll
    for (int d = 32; d > 0; d >>= 1) s += __shfl_down(s, d);
    __shared__ int wsum[4];
    if ((tid & 63) == 0) wsum[tid >> 6] = s;
    __syncthreads();
    if (tid == 0) csum[b] = wsum[0] + wsum[1] + wsum[2] + wsum[3];
}

__global__ void k_scan_chunks(const int* __restrict__ csum, int* __restrict__ cofs) {
    if (threadIdx.x == 0 && blockIdx.x == 0) {
        int acc = 0;
        for (int i = 0; i < NCHUNK; ++i) { cofs[i] = acc; acc += csum[i]; }
    }
}

__global__ __launch_bounds__(256) void k_chunk_scan(const int* __restrict__ counts,
                                                    const int* __restrict__ cofs,
                                                    int* __restrict__ offs,
                                                    int* __restrict__ cursor) {
    const int b = blockIdx.x, tid = threadIdx.x;
    const int lane = tid & 63, wv = tid >> 6;
    const int base = b * 1024 + tid * 4;
    int c[4];
#pragma unroll
    for (int j = 0; j < 4; ++j) {
        const int i = base + j;
        c[j] = (i < NN) ? counts[i] : 0;
    }
    const int ls = c[0] + c[1] + c[2] + c[3];
    int v = ls;
#pragma unroll
    for (int d = 1; d < 64; d <<= 1) {
        const int u = __shfl_up(v, d);
        if (lane >= d) v += u;
    }
    __shared__ int wsum[4];
    if (lane == 63) wsum[wv] = v;
    __syncthreads();
    int wbase = 0;
    for (int w = 0; w < wv; ++w) wbase += wsum[w];
    int excl = cofs[b] + wbase + (v - ls);
#pragma unroll
    for (int j = 0; j < 4; ++j) {
        const int i = base + j;
        if (i < NN) { offs[i] = excl; cursor[i] = excl; }
        excl += c[j];
    }
}

// Fill CSR slots: epack[pos] = {edge, src, bits(ci[src]), 0} — one 16B write.
__global__ __launch_bounds__(256) void k_permfill(const int* __restrict__ dst,
                                                  const int* __restrict__ src,
                                                  const float* __restrict__ ci,
                                                  int* __restrict__ cursor,
                                                  int4* __restrict__ epack) {
    for (int e = blockIdx.x * blockDim.x + threadIdx.x; e < NE;
         e += gridDim.x * blockDim.x) {
        const int s = src[e];
        const float cs = ci[s];
        const int pos = atomicAdd(&cursor[dst[e]], 1);
        epack[pos] = make_int4(e, s, __float_as_int(cs), 0);
    }
}

// ---------- Fused pull + node-GEMM ----------
// Block = 256 threads = 16 quarters = 16 nodes = one MFMA A-tile.
// Unroll-2: two independent accumulator chains per quarter.
__global__ __launch_bounds__(256) void k_pull_fused(
    const int4* __restrict__ epack, const int* __restrict__ offs,
    const int* __restrict__ counts, const float* __restrict__ review,
    const float* __restrict__ ci,
    const __bf16* __restrict__ f2c, const __bf16* __restrict__ f3c,
    const float* __restrict__ W1, const float* __restrict__ W2,
    float* __restrict__ out_rst, float* __restrict__ out_re,
    float* __restrict__ out_id)
{
    __shared__ __bf16 At[16][64];   // bf16(cid * hx) tile
    __shared__ float  S2[16][64];   // cid * sum(f2c[s]) tile

    const int tid = threadIdx.x;
    const int l16 = tid & 15;
    const int q   = tid >> 4;               // node-in-block
    const int n   = blockIdx.x * 16 + q;

    const int beg = offs[n];
    const int cnt = counts[n];

    float4 ax0 = {0,0,0,0}, a20 = {0,0,0,0}, a30 = {0,0,0,0};
    float4 ax1 = {0,0,0,0}, a21 = {0,0,0,0}, a31 = {0,0,0,0};

    int k = 0;
    for (; k + 2 <= cnt; k += 2) {
        const int4 ea = epack[beg + k];
        const int4 eb = epack[beg + k + 1];
        const float ca = __int_as_float(ea.z);
        const float cb = __int_as_float(eb.z);
        const float4 ra = *reinterpret_cast<const float4*>(review + (size_t)ea.x * DD + l16 * 4);
        const float4 rb = *reinterpret_cast<const float4*>(review + (size_t)eb.x * DD + l16 * 4);
        const bf16x4 p2a = *reinterpret_cast<const bf16x4*>(f2c + (size_t)ea.y * DD + l16 * 4);
        const bf16x4 p2b = *reinterpret_cast<const bf16x4*>(f2c + (size_t)eb.y * DD + l16 * 4);
        const bf16x4 p3a = *reinterpret_cast<const bf16x4*>(f3c + (size_t)ea.y * DD + l16 * 4);
        const bf16x4 p3b = *reinterpret_cast<const bf16x4*>(f3c + (size_t)eb.y * DD + l16 * 4);
        ax0.x = fmaf(ra.x, ca, ax0.x); ax0.y = fmaf(ra.y, ca, ax0.y);
        ax0.z = fmaf(ra.z, ca, ax0.z); ax0.w = fmaf(ra.w, ca, ax0.w);
        ax1.x = fmaf(rb.x, cb, ax1.x); ax1.y = fmaf(rb.y, cb, ax1.y);
        ax1.z = fmaf(rb.z, cb, ax1.z); ax1.w = fmaf(rb.w, cb, ax1.w);
        a20.x += (float)p2a[0]; a20.y += (float)p2a[1];
        a20.z += (float)p2a[2]; a20.w += (float)p2a[3];
        a21.x += (float)p2b[0]; a21.y += (float)p2b[1];
        a21.z += (float)p2b[2]; a21.w += (float)p2b[3];
        a30.x += (float)p3a[0]; a30.y += (float)p3a[1];
        a30.z += (float)p3a[2]; a30.w += (float)p3a[3];
        a31.x += (float)p3b[0]; a31.y += (float)p3b[1];
        a31.z += (float)p3b[2]; a31.w += (float)p3b[3];
    }
    if (k < cnt) {
        const int4 ea = epack[beg + k];
        const float ca = __int_as_float(ea.z);
        const float4 ra = *reinterpret_cast<const float4*>(review + (size_t)ea.x * DD + l16 * 4);
        const bf16x4 p2a = *reinterpret_cast<const bf16x4*>(f2c + (size_t)ea.y * DD + l16 * 4);
        const bf16x4 p3a = *reinterpret_cast<const bf16x4*>(f3c + (size_t)ea.y * DD + l16 * 4);
        ax0.x = fmaf(ra.x, ca, ax0.x); ax0.y = fmaf(ra.y, ca, ax0.y);
        ax0.z = fmaf(ra.z, ca, ax0.z); ax0.w = fmaf(ra.w, ca, ax0.w);
        a20.x += (float)p2a[0]; a20.y += (float)p2a[1];
        a20.z += (float)p2a[2]; a20.w += (float)p2a[3];
        a30.x += (float)p3a[0]; a30.y += (float)p3a[1];
        a30.z += (float)p3a[2]; a30.w += (float)p3a[3];
    }

    const float cid = ci[n];
    float4 ax = {ax0.x + ax1.x, ax0.y + ax1.y, ax0.z + ax1.z, ax0.w + ax1.w};
    float4 a2 = {a20.x + a21.x, a20.y + a21.y, a20.z + a21.z, a20.w + a21.w};
    float4 a3 = {a30.x + a31.x, a30.y + a31.y, a30.z + a31.z, a30.w + a31.w};

    // out_id is final here.
    float4 v3 = {a3.x * cid, a3.y * cid, a3.z * cid, a3.w * cid};
    *reinterpret_cast<float4*>(out_id + (size_t)n * DD + l16 * 4) = v3;

    // Stage GEMM input tiles.
    bf16x4 hb;
    hb[0] = (__bf16)(ax.x * cid); hb[1] = (__bf16)(ax.y * cid);
    hb[2] = (__bf16)(ax.z * cid); hb[3] = (__bf16)(ax.w * cid);
    *reinterpret_cast<bf16x4*>(&At[q][l16 * 4]) = hb;
    float4 s2v = {a2.x * cid, a2.y * cid, a2.z * cid, a2.w * cid};
    *reinterpret_cast<float4*>(&S2[q][l16 * 4]) = s2v;
    __syncthreads();

    // GEMM: wave w computes col-block w for both W1 (out_re) and W2 (out_rst).
    const int w  = tid >> 6;          // 0..3
    const int lq = (tid & 63) >> 4;   // 0..3
    bf16x8 w1f[2], w2f[2];
#pragma unroll
    for (int kk = 0; kk < 2; ++kk) {
        const int off = (w * 16 + l16) * DD + kk * 32 + lq * 8;
        w1f[kk] = pack8(W1 + off);
        w2f[kk] = pack8(W2 + off);
    }
    const bf16x8 a0 = *reinterpret_cast<const bf16x8*>(&At[l16][lq * 8]);
    const bf16x8 a1 = *reinterpret_cast<const bf16x8*>(&At[l16][lq * 8 + 32]);

    const f32x4 zero = {0.f, 0.f, 0.f, 0.f};
    f32x4 acc1 = zero, acc2 = zero;
    acc1 = __builtin_amdgcn_mfma_f32_16x16x32_bf16(a0, w1f[0], acc1, 0, 0, 0);
    acc1 = __builtin_amdgcn_mfma_f32_16x16x32_bf16(a1, w1f[1], acc1, 0, 0, 0);
    acc2 = __builtin_amdgcn_mfma_f32_16x16x32_bf16(a0, w2f[0], acc2, 0, 0, 0);
    acc2 = __builtin_amdgcn_mfma_f32_16x16x32_bf16(a1, w2f[1], acc2, 0, 0, 0);

    const int base = blockIdx.x * 16;
#pragma unroll
    for (int i = 0; i < 4; ++i) {
        const int row = lq * 4 + i;
        const size_t o = (size_t)(base + row) * DD + w * 16 + l16;
        out_re[o]  = acc1[i];
        out_rst[o] = acc2[i] + S2[row][w * 16 + l16];
    }
}

// ---------- Fallback (round-2 proven kernel) if ws too small ----------
__global__ __launch_bounds__(256) void gcn_mfma_kernel(
    const int* __restrict__ src, const int* __restrict__ dst,
    const float* __restrict__ review, const float* __restrict__ ci,
    const float* __restrict__ W1, const float* __restrict__ W2,
    const float* __restrict__ f2, const float* __restrict__ f3,
    float* __restrict__ out)
{
    float* out_rst = out;
    float* out_re  = out + (size_t)NN * DD;
    float* out_id  = out + 2 * (size_t)NN * DD;
    const int lane = threadIdx.x & 63;
    const int l16  = lane & 15;
    const int lq   = lane >> 4;
    const int wid  = blockIdx.x * (blockDim.x >> 6) + (threadIdx.x >> 6);
    const int nw   = gridDim.x * (blockDim.x >> 6);

    bf16x8 w1f[4][2], w2f[4][2];
#pragma unroll
    for (int c = 0; c < 4; ++c)
#pragma unroll
        for (int kk = 0; kk < 2; ++kk) {
            const int off = (c * 16 + l16) * DD + kk * 32 + lq * 8;
            w1f[c][kk] = pack8(W1 + off);
            w2f[c][kk] = pack8(W2 + off);
        }
    const f32x4 zero = {0.f, 0.f, 0.f, 0.f};
    for (int t = wid; t < NE / 16; t += nw) {
        const int e0 = t * 16;
        const float* xr = review + (size_t)(e0 + l16) * DD + lq * 8;
        const bf16x8 a0 = pack8(xr);
        const bf16x8 a1 = pack8(xr + 32);
        f32x4 acc1[4], acc2[4];
#pragma unroll
        for (int c = 0; c < 4; ++c) { acc1[c] = zero; acc2[c] = zero; }
#pragma unroll
        for (int c = 0; c < 4; ++c) {
            acc1[c] = __builtin_amdgcn_mfma_f32_16x16x32_bf16(a0, w1f[c][0], acc1[c], 0, 0, 0);
            acc1[c] = __builtin_amdgcn_mfma_f32_16x16x32_bf16(a1, w1f[c][1], acc1[c], 0, 0, 0);
            acc2[c] = __builtin_amdgcn_mfma_f32_16x16x32_bf16(a0, w2f[c][0], acc2[c], 0, 0, 0);
            acc2[c] = __builtin_amdgcn_mfma_f32_16x16x32_bf16(a1, w2f[c][1], acc2[c], 0, 0, 0);
        }
        int sA[4], dA[4]; float cf[4];
#pragma unroll
        for (int i = 0; i < 4; ++i) {
            const int e = e0 + lq * 4 + i;
            sA[i] = src[e]; dA[i] = dst[e];
            cf[i] = ci[sA[i]] * ci[dA[i]];
        }
#pragma unroll
        for (int i = 0; i < 4; ++i) {
            const size_t so = (size_t)sA[i] * DD;
            const size_t dofs = (size_t)dA[i] * DD;
            const float c_ = cf[i];
#pragma unroll
            for (int c = 0; c < 4; ++c) {
                const int col = c * 16 + l16;
                atomicAdd(out_re  + dofs + col, acc1[c][i] * c_);
                atomicAdd(out_rst + dofs + col, (f2[so + col] + acc2[c][i]) * c_);
                atomicAdd(out_id  + dofs + col, f3[so + col] * c_);
            }
        }
    }
}

extern "C" void kernel_launch(void* const* d_in, const int* in_sizes, int n_in,
                              void* d_out, int out_size, void* d_ws, size_t ws_size,
                              hipStream_t stream) {
    const int*   src    = (const int*)d_in[0];
    const int*   dst    = (const int*)d_in[1];
    const float* review = (const float*)d_in[2];
    const float* ci     = (const float*)d_in[3];
    // d_in[4] = feature (unused by the reference computation)
    const float* W1     = (const float*)d_in[5];
    const float* W2     = (const float*)d_in[6];
    const float* f2     = (const float*)d_in[7];
    const float* f3     = (const float*)d_in[8];
    float* out = (float*)d_out;
    float* out_rst = out;
    float* out_re  = out + (size_t)NN * DD;
    float* out_id  = out + 2 * (size_t)NN * DD;

    // counts | offs | cursor | csum | cofs | epack(int4) | f2c | f3c
    const size_t NEED = sizeof(int) * ((size_t)3 * NN + 512) +
                        sizeof(int4) * (size_t)NE +
                        2 * sizeof(__bf16) * (size_t)NN * DD;
    if (ws_size < NEED) {
        hipMemsetAsync(out, 0, (size_t)out_size * sizeof(float), stream);
        gcn_mfma_kernel<<<2048, 256, 0, stream>>>(src, dst, review, ci, W1, W2, f2, f3, out);
        return;
    }

    char* w = (char*)d_ws;
    int* counts = (int*)w;    w += (size_t)NN * 4;
    int* offs   = (int*)w;    w += (size_t)NN * 4;
    int* cursor = (int*)w;    w += (size_t)NN * 4;
    int* csum   = (int*)w;    w += 256 * 4;
    int* cofs   = (int*)w;    w += 256 * 4;
    int4* epack = (int4*)w;   w += (size_t)NE * 16;
    __bf16* f2c = (__bf16*)w; w += (size_t)NN * DD * 2;
    __bf16* f3c = (__bf16*)w;

    hipMemsetAsync(counts, 0, (size_t)NN * 4, stream);
    k_prep      <<<3072, 256, 0, stream>>>(dst, f2, f3, ci, counts, f2c, f3c);
    k_chunk_sums<<<NCHUNK, 256, 0, stream>>>(counts, csum);
    k_scan_chunks<<<1, 64, 0, stream>>>(csum, cofs);
    k_chunk_scan<<<NCHUNK, 256, 0, stream>>>(counts, cofs, offs, cursor);
    k_permfill  <<<1024, 256, 0, stream>>>(dst, src, ci, cursor, epack);
    k_pull_fused<<<NN / 16, 256, 0, stream>>>(epack, offs, counts, review, ci,
                                              f2c, f3c, W1, W2,
                                              out_rst, out_re, out_id);
}